// Round 17
// baseline (72.720 us; speedup 1.0000x reference)
//
#include <hip/hip_runtime.h>
#include <hip/hip_bf16.h>

typedef __attribute__((ext_vector_type(8))) short bf16x8;
typedef __attribute__((ext_vector_type(4))) float f32x4;

#define B_ROWS 8192
#define NROWS 16384             // 2B
#define D 128
#define C1 2.8853900817779268f  // 2*log2(e)  (sim = 2*cos; exp(x)=2^(x*log2e))
#define E_M2 0.13533528323661270f // exp(-2) == 2^(-C1): the folded row-max shift
#define RSCALE 1.6986436f       // sqrt(C1), folded into reps on both operands
#define TILE_COLS 128
#define TILE_BYTES (TILE_COLS * D * 2) // 32 KB per buffer
#define NSPLIT 16               // lists per row-chunk
#define NBLK (64 * NSPLIT)      // 1024
#define NSLICE 8

// Raw hardware exp2/log2: args are bounded, no range handling needed.
__device__ __forceinline__ float fast_exp2(float x) {
#if __has_builtin(__builtin_amdgcn_exp2f)
    return __builtin_amdgcn_exp2f(x);
#else
    float r; asm("v_exp_f32 %0, %1" : "=v"(r) : "v"(x)); return r;
#endif
}
__device__ __forceinline__ float fast_log2(float x) {
#if __has_builtin(__builtin_amdgcn_logf)
    return __builtin_amdgcn_logf(x);
#else
    float r; asm("v_log_f32 %0, %1" : "=v"(r) : "v"(x)); return r;
#endif
}

__device__ __forceinline__ unsigned short f2bf(float f) {
    union { float f; unsigned u; } v; v.f = f;
    unsigned r = v.u + 0x7FFFu + ((v.u >> 16) & 1u); // RNE
    return (unsigned short)(r >> 16);
}

// triangular colpart offset: slab I holds cols [256(I+1), NROWS)
__device__ __host__ __forceinline__ int colpart_off(int I) {
    return I * NROWS - 128 * I * (I + 1);
}

// K1: row norms + positive dots + bf16 reps (pre-scaled by sqrt(C1)).
__global__ __launch_bounds__(256) void k_norm(const float* __restrict__ zi,
                                              const float* __restrict__ zj,
                                              unsigned* __restrict__ repsU,
                                              float* __restrict__ pos) {
    int w = threadIdx.x >> 6, lane = threadIdx.x & 63;
    int row = blockIdx.x * 4 + w;
    const float2* a2 = (const float2*)(zi + (size_t)row * D);
    const float2* b2 = (const float2*)(zj + (size_t)row * D);
    float2 a = a2[lane], b = b2[lane];
    float si = a.x * a.x + a.y * a.y;
    float sj = b.x * b.x + b.y * b.y;
    float sd = a.x * b.x + a.y * b.y;
#pragma unroll
    for (int m = 32; m; m >>= 1) {
        si += __shfl_xor(si, m);
        sj += __shfl_xor(sj, m);
        sd += __shfl_xor(sd, m);
    }
    float inv_i = 1.0f / fmaxf(sqrtf(si), 1e-12f);
    float inv_j = 1.0f / fmaxf(sqrtf(sj), 1e-12f);
    float sa = inv_i * RSCALE, sb = inv_j * RSCALE;
    repsU[(size_t)row * 64 + lane] =
        (unsigned)f2bf(a.x * sa) | ((unsigned)f2bf(a.y * sa) << 16);
    repsU[(size_t)(row + B_ROWS) * 64 + lane] =
        (unsigned)f2bf(b.x * sb) | ((unsigned)f2bf(b.y * sb) << 16);
    if (lane == 0) pos[row] = fast_exp2(sd * inv_i * inv_j * C1); // exp(2*cos_ij)
}

// K2: symmetric-half fused sim-GEMM + exp + row/col sums — m201-style
// 2-PHASE-PER-TILE counted-vmcnt pipeline (R16 lesson: residual stall scales
// with work under any coarse schedule; m233/m218: only the fine per-phase
// {partial-STAGE || ds_read || MFMA} interleave with vmcnt never 0 removes it).
// 128-col tile = 2 half-tiles (ct 0-3 / 4-7). Staging loads j cover half j>>2
// (dst=(j*4+w)*1024). Per phase: vmcnt(4)+lgkmcnt(0) -> s_barrier -> issue 4
// staging loads (tile t+1, same half) -> ds_read + setprio(1) MFMA/exp.
// Uniform vmcnt(4): oldest 4 outstanding = the half about to be read.
// C/D layout (m89-verified): row=(lane>>4)*4+q, col=lane&15.
__global__ __launch_bounds__(256, 2) void k_negsum(const unsigned short* __restrict__ R,
                                                   float* __restrict__ rowpart,
                                                   float* __restrict__ colpart) {
    __shared__ char smem[2][TILE_BYTES];    // 64 KB
    __shared__ float colacc[2][16][16][8];  // 16 KB [parity][w*4+lk][lr][ct]
    int I = blockIdx.x >> 4;
    int s = blockIdx.x & (NSPLIT - 1);
    int rowBase = I << 8;
    int j0 = I << 1;                        // first owned 128-col tile
    int dph = (s - (j0 & 15)) & 15;
    int jstart = j0 + dph;                  // first tile of this list
    int nt = (jstart < 128) ? (((127 - jstart) >> 4) + 1) : 0;

    int w = threadIdx.x >> 6;
    int lane = threadIdx.x & 63;
    int lr = lane & 15, lk = lane >> 4;
    int waveRow = rowBase + (w << 6);

    bf16x8 afrag[4][4];
#pragma unroll
    for (int r = 0; r < 4; ++r)
#pragma unroll
        for (int kk = 0; kk < 4; ++kk)
            afrag[r][kk] = *(const bf16x8*)(R + (size_t)(waveRow + r * 16 + lr) * D + kk * 32 + lk * 8);

    // staging: load j of wave w covers dest bytes (j*4+w)*1024 + lane*16
    // -> loads 0-3 cover ct 0-3 (first 16KB), loads 4-7 cover ct 4-7.
    int srcoff[8], dstoff[8];
#pragma unroll
    for (int j = 0; j < 8; ++j) {
        int o = (j * 4 + w) * 1024 + lane * 16;
        int row = o >> 8, c = o & 255;
        srcoff[j] = row * 256 + (c ^ ((row & 7) << 4)); // pre-swizzled global source
        dstoff[j] = (j * 4 + w) * 1024;                 // wave-uniform LDS base
    }

    const char* Rb = (const char*)R;

    // swizzled read-offset components: lds_off(ct,kk) = ct*4096 + lbase + (kk*64 ^ m64)
    int m64 = (lr & 4) << 4;
    int lbase = lr * 256 + ((lk * 16) ^ ((lr & 3) << 4));

    float acc[4][4] = {};

    // issue the 4 staging loads of half h for (clamped) tile v into smem[(v)&1]
#define STAGE_HALF(v, h)                                                          \
    do {                                                                          \
        int vc_ = (v) < nt ? (v) : nt - 1;                                        \
        char* dbase_ = &smem[(v) & 1][0];                                         \
        const char* tb_ = Rb + (size_t)(jstart + (vc_ << 4)) * TILE_BYTES;        \
        _Pragma("unroll")                                                         \
        for (int j = (h) * 4; j < (h) * 4 + 4; ++j)                               \
            __builtin_amdgcn_global_load_lds(                                     \
                (const __attribute__((address_space(1))) unsigned*)(tb_ + srcoff[j]), \
                (__attribute__((address_space(3))) unsigned*)(dbase_ + dstoff[j]), \
                16, 0, 0);                                                        \
    } while (0)

    // one 4-ct half; bf regs live only within one ct iteration (R15 lesson)
#define BATCH_HALF(H, DIAG)                                                       \
    do {                                                                          \
        _Pragma("unroll")                                                         \
        for (int ct = (H) * 4; ct < (H) * 4 + 4; ++ct) {                          \
            const char* cb_ = sb + ct * 4096;                                     \
            bf16x8 b0 = *(const bf16x8*)(cb_ + (0 ^ m64));                        \
            bf16x8 b1 = *(const bf16x8*)(cb_ + (64 ^ m64));                       \
            bf16x8 b2 = *(const bf16x8*)(cb_ + (128 ^ m64));                      \
            bf16x8 b3 = *(const bf16x8*)(cb_ + (192 ^ m64));                      \
            _Pragma("unroll")                                                     \
            for (int r = 0; r < 4; ++r) {                                         \
                f32x4 c = {0.f, 0.f, 0.f, 0.f};                                   \
                c = __builtin_amdgcn_mfma_f32_16x16x32_bf16(afrag[r][0], b0, c, 0, 0, 0); \
                c = __builtin_amdgcn_mfma_f32_16x16x32_bf16(afrag[r][1], b1, c, 0, 0, 0); \
                c = __builtin_amdgcn_mfma_f32_16x16x32_bf16(afrag[r][2], b2, c, 0, 0, 0); \
                c = __builtin_amdgcn_mfma_f32_16x16x32_bf16(afrag[r][3], b3, c, 0, 0, 0); \
                if (DIAG && ct == ctd + r) {                                      \
                    _Pragma("unroll")                                             \
                    for (int q = 0; q < 4; ++q)                                   \
                        if (lk * 4 + q != lr) {                                   \
                            float e = fast_exp2(c[q]);                            \
                            acc[r][q] += e; csum[ct] += e;                        \
                        }                                                         \
                } else {                                                          \
                    _Pragma("unroll")                                             \
                    for (int q = 0; q < 4; ++q) {                                 \
                        float e = fast_exp2(c[q]);                                \
                        acc[r][q] += e; csum[ct] += e;                            \
                    }                                                             \
                }                                                                 \
            }                                                                     \
        }                                                                         \
    } while (0)

    if (nt > 0) {
        STAGE_HALF(0, 0);                    // prologue: tile 0, both halves,
        STAGE_HALF(0, 1);                    // in half order (vmcnt counts on it)
        for (int t = 0; t < nt; ++t) {
            int jt = jstart + (t << 4);
            int colBase = jt << 7;
            const char* sb = &smem[t & 1][0] + lbase;
            float csum[8] = {};
            bool dg = (unsigned)(waveRow - colBase) < 128u;  // wave-uniform
            int ctd = (waveRow - colBase) >> 4;              // valid when dg

            // ---- phase 0: half 0 ----
            asm volatile("s_waitcnt vmcnt(4) lgkmcnt(0)" ::: "memory");
            __builtin_amdgcn_s_barrier();    // half 0 of tile t visible to all
            STAGE_HALF(t + 1, 0);            // overwrite-safe: buf (t+1)&1 not read
            // flush PREVIOUS tile's column partials (one rotating wave)
            if (t > 0 && w == ((t + 3) & 3)) {
                int pcb = colBase - 2048;    // (jt-16)<<7
                if (pcb >= rowBase + 256) {
                    int par = (t - 1) & 1;
                    float v0 = 0.f, v1 = 0.f;
#pragma unroll
                    for (int u = 0; u < 16; ++u) {
                        v0 += colacc[par][u][lane & 15][lane >> 4];
                        v1 += colacc[par][u][lane & 15][4 + (lane >> 4)];
                    }
                    int cb = colpart_off(I) + pcb - ((I + 1) << 8);
                    colpart[cb + lane] = v0;
                    colpart[cb + 64 + lane] = v1;
                }
            }
            __builtin_amdgcn_s_setprio(1);
            if (dg) { BATCH_HALF(0, true); } else { BATCH_HALF(0, false); }
            __builtin_amdgcn_s_setprio(0);

            // ---- phase 1: half 1 ----
            asm volatile("s_waitcnt vmcnt(4) lgkmcnt(0)" ::: "memory");
            __builtin_amdgcn_s_barrier();    // half 1 of tile t visible to all
            STAGE_HALF(t + 1, 1);
            __builtin_amdgcn_s_setprio(1);
            if (dg) { BATCH_HALF(1, true); } else { BATCH_HALF(1, false); }
            __builtin_amdgcn_s_setprio(0);

            bool offdiag = (colBase >= rowBase + 256);
            if (offdiag) {                   // two b128 per lane, conflict-free
                int par = t & 1;
                f32x4 cs0 = {csum[0], csum[1], csum[2], csum[3]};
                f32x4 cs1 = {csum[4], csum[5], csum[6], csum[7]};
                *(f32x4*)&colacc[par][(w << 2) | lk][lr][0] = cs0;
                *(f32x4*)&colacc[par][(w << 2) | lk][lr][4] = cs1;
            }
        }
        __syncthreads();                     // epilogue: full drain once
        if (w == ((nt + 3) & 3)) {           // flush last tile's column partials
            int pcb = (jstart + ((nt - 1) << 4)) << 7;
            if (pcb >= rowBase + 256) {
                int par = (nt - 1) & 1;
                float v0 = 0.f, v1 = 0.f;
#pragma unroll
                for (int u = 0; u < 16; ++u) {
                    v0 += colacc[par][u][lane & 15][lane >> 4];
                    v1 += colacc[par][u][lane & 15][4 + (lane >> 4)];
                }
                int cb = colpart_off(I) + pcb - ((I + 1) << 8);
                colpart[cb + lane] = v0;
                colpart[cb + 64 + lane] = v1;
            }
        }
    }
#undef STAGE_HALF
#undef BATCH_HALF

    // reduce the 16 col-lanes of each row group, write deterministic row partials
    // (empty lists still write zeros so k_negred can sum all 16 slabs)
#pragma unroll
    for (int r = 0; r < 4; ++r)
#pragma unroll
        for (int q = 0; q < 4; ++q) {
            float v = acc[r][q];
            v += __shfl_xor(v, 1);
            v += __shfl_xor(v, 2);
            v += __shfl_xor(v, 4);
            v += __shfl_xor(v, 8);
            if (lr == 0)
                rowpart[(size_t)s * NROWS + waveRow + r * 16 + lk * 4 + q] = v;
        }
}

// K2b: slice-parallel partial reduction of rowpart+colpart -> negp[8][N].
// 512 blocks; <=10 independent coalesced loads per thread.
__global__ __launch_bounds__(256) void k_negred(const float* __restrict__ rowpart,
                                                const float* __restrict__ colpart,
                                                float* __restrict__ negp) {
    int g = blockIdx.x >> 3;                // row group: rows [256g, 256g+256)
    int z = blockIdx.x & (NSLICE - 1);
    int i = g * 256 + threadIdx.x;
    float a = 0.f;
#pragma unroll
    for (int s = z; s < NSPLIT; s += NSLICE) // 2 iterations
        a += rowpart[(size_t)s * NROWS + i];
    for (int I = z; I < g; I += NSLICE)      // <=8 iterations
        a += colpart[colpart_off(I) + i - ((I + 1) << 8)];
    negp[(size_t)z * NROWS + i] = a;
}

// K3a: per-row loss terms + block partial sums. 64 blocks x 256 threads.
__global__ __launch_bounds__(256) void k_loss1(const float* __restrict__ pos,
                                               const float* __restrict__ negp,
                                               float* __restrict__ bsum) {
    int i = blockIdx.x * 256 + threadIdx.x;
    float neg = 0.f;
#pragma unroll
    for (int z = 0; z < NSLICE; ++z) neg += negp[(size_t)z * NROWS + i];
    neg *= E_M2; // folded (sim - 2.0) shift
    float p = pos[i & (B_ROWS - 1)];
    float Ng = fmaxf((neg - 819.2f * p) * (1.0f / 0.9f), 8192.0f * E_M2);
    float l = fast_log2((p + Ng + 1e-8f) / p) * 0.69314718056f; // = -log(p/(p+Ng+eps))
#pragma unroll
    for (int m = 32; m; m >>= 1) l += __shfl_xor(l, m);
    __shared__ float s4[4];
    int wv = threadIdx.x >> 6;
    if ((threadIdx.x & 63) == 0) s4[wv] = l;
    __syncthreads();
    if (threadIdx.x == 0) bsum[blockIdx.x] = s4[0] + s4[1] + s4[2] + s4[3];
}

// K3b: final reduce of 64 block sums. 1 block, 1 wave.
__global__ void k_loss2(const float* __restrict__ bsum, float* __restrict__ out) {
    float v = bsum[threadIdx.x];
#pragma unroll
    for (int m = 32; m; m >>= 1) v += __shfl_xor(v, m);
    if (threadIdx.x == 0) out[0] = v * (1.0f / (float)NROWS);
}

extern "C" void kernel_launch(void* const* d_in, const int* in_sizes, int n_in,
                              void* d_out, int out_size, void* d_ws, size_t ws_size,
                              hipStream_t stream) {
    const float* zi = (const float*)d_in[0];
    const float* zj = (const float*)d_in[1];
    char* ws = (char*)d_ws;
    unsigned short* reps = (unsigned short*)ws;            // 4 MB
    float* pos = (float*)(ws + 4194304);                   // 32 KB
    float* rowpart = pos + B_ROWS;                         // 16*16384*4 = 1 MB
    float* colpart = rowpart + (size_t)NSPLIT * NROWS;     // 516096*4 ~= 2 MB (triangular)
    float* negp = colpart + 516096;                        // 8*16384*4 = 512 KB
    float* bsum = negp + (size_t)NSLICE * NROWS;           // 256 B
    float* out = (float*)d_out;                            // total ~7.6 MB

    k_norm<<<B_ROWS / 4, 256, 0, stream>>>(zi, zj, (unsigned*)reps, pos);
    k_negsum<<<NBLK, 256, 0, stream>>>(reps, rowpart, colpart);
    k_negred<<<64 * NSLICE, 256, 0, stream>>>(rowpart, colpart, negp);
    k_loss1<<<NROWS / 256, 256, 0, stream>>>(pos, negp, bsum);
    k_loss2<<<1, 64, 0, stream>>>(bsum, out);
}

// Round 18
// 64.948 us; speedup vs baseline: 1.1197x; 1.1197x over previous
//
#include <hip/hip_runtime.h>
#include <hip/hip_bf16.h>

typedef __attribute__((ext_vector_type(8))) short bf16x8;
typedef __attribute__((ext_vector_type(4))) float f32x4;
typedef __attribute__((ext_vector_type(2))) float f32x2;

#define B_ROWS 8192
#define NROWS 16384             // 2B
#define D 128
#define C1 2.8853900817779268f  // 2*log2(e)  (sim = 2*cos; exp(x)=2^(x*log2e))
#define E_M2 0.13533528323661270f // exp(-2) == 2^(-C1): the folded row-max shift
#define RSCALE 1.6986436f       // sqrt(C1), folded into reps on both operands
#define TILE_COLS 32
#define TILE_BYTES (TILE_COLS * D * 2) // 8 KB per buffer
#define NSPLIT 16               // lists per row-chunk
#define NBLK (64 * NSPLIT)      // 1024
#define NSLICE 8

// Raw hardware exp2/log2: args are bounded, no range handling needed.
__device__ __forceinline__ float fast_exp2(float x) {
#if __has_builtin(__builtin_amdgcn_exp2f)
    return __builtin_amdgcn_exp2f(x);
#else
    float r; asm("v_exp_f32 %0, %1" : "=v"(r) : "v"(x)); return r;
#endif
}
__device__ __forceinline__ float fast_log2(float x) {
#if __has_builtin(__builtin_amdgcn_logf)
    return __builtin_amdgcn_logf(x);
#else
    float r; asm("v_log_f32 %0, %1" : "=v"(r) : "v"(x)); return r;
#endif
}

__device__ __forceinline__ unsigned short f2bf(float f) {
    union { float f; unsigned u; } v; v.f = f;
    unsigned r = v.u + 0x7FFFu + ((v.u >> 16) & 1u); // RNE
    return (unsigned short)(r >> 16);
}

// triangular colpart offset: slab I holds cols [256(I+1), NROWS)
__device__ __host__ __forceinline__ int colpart_off(int I) {
    return I * NROWS - 128 * I * (I + 1);
}

// K1: row norms + positive dots + bf16 reps (pre-scaled by sqrt(C1)).
__global__ __launch_bounds__(256) void k_norm(const float* __restrict__ zi,
                                              const float* __restrict__ zj,
                                              unsigned* __restrict__ repsU,
                                              float* __restrict__ pos) {
    int w = threadIdx.x >> 6, lane = threadIdx.x & 63;
    int row = blockIdx.x * 4 + w;
    const float2* a2 = (const float2*)(zi + (size_t)row * D);
    const float2* b2 = (const float2*)(zj + (size_t)row * D);
    float2 a = a2[lane], b = b2[lane];
    float si = a.x * a.x + a.y * a.y;
    float sj = b.x * b.x + b.y * b.y;
    float sd = a.x * b.x + a.y * b.y;
#pragma unroll
    for (int m = 32; m; m >>= 1) {
        si += __shfl_xor(si, m);
        sj += __shfl_xor(sj, m);
        sd += __shfl_xor(sd, m);
    }
    float inv_i = 1.0f / fmaxf(sqrtf(si), 1e-12f);
    float inv_j = 1.0f / fmaxf(sqrtf(sj), 1e-12f);
    float sa = inv_i * RSCALE, sb = inv_j * RSCALE;
    repsU[(size_t)row * 64 + lane] =
        (unsigned)f2bf(a.x * sa) | ((unsigned)f2bf(a.y * sa) << 16);
    repsU[(size_t)(row + B_ROWS) * 64 + lane] =
        (unsigned)f2bf(b.x * sb) | ((unsigned)f2bf(b.y * sb) << 16);
    if (lane == 0) pos[row] = fast_exp2(sd * inv_i * inv_j * C1); // exp(2*cos_ij)
}

// K2: symmetric-half fused sim-GEMM + exp + row/col sums — SMALL-LDS variant
// to unlock cross-block TLP. R17 lesson: five schedule interventions were
// null/negative; wall = VALU+MFMA+LDS run SEQUENTIALLY (sum of pipes = wall)
// because ~1.5 waves/SIMD effective. All prior "occupancy" A/Bs kept
// LDS_Block_Size at 32-80KB (possibly coarse alloc granule -> always 2
// blocks/CU). This config: 20.5KB LDS/block (2x8KB dbuf + 4KB colacc),
// ~110 VGPR -> up to 5 independent blocks/CU = 5 waves/SIMD, each a
// different block (no shared barrier) -> pipes can finally overlap.
// 32-col tiles; same per-element work, swizzle, staging as R11.
// C/D layout (m89-verified): row=(lane>>4)*4+q, col=lane&15.
__global__ __launch_bounds__(256, 2) void k_negsum(const unsigned short* __restrict__ R,
                                                   float* __restrict__ rowpart,
                                                   float* __restrict__ colpart) {
    __shared__ char smem[2][TILE_BYTES];    // 16 KB
    __shared__ float colacc[2][16][16][2];  // 4 KB [parity][w*4+lk][lr][ct]
    int I = blockIdx.x >> 4;
    int s = blockIdx.x & (NSPLIT - 1);
    int rowBase = I << 8;
    int j0 = I << 3;                        // first owned 32-col tile
    int dph = (s - (j0 & 15)) & 15;
    int jstart = j0 + dph;                  // first tile of this list
    int nt = (jstart < 512) ? (((511 - jstart) >> 4) + 1) : 0;

    int w = threadIdx.x >> 6;
    int lane = threadIdx.x & 63;
    int lr = lane & 15, lk = lane >> 4;
    int waveRow = rowBase + (w << 6);

    bf16x8 afrag[4][4];
#pragma unroll
    for (int r = 0; r < 4; ++r)
#pragma unroll
        for (int kk = 0; kk < 4; ++kk)
            afrag[r][kk] = *(const bf16x8*)(R + (size_t)(waveRow + r * 16 + lr) * D + kk * 32 + lk * 8);

    // staging: instruction j of wave w covers dest bytes (w*2+j)*1024 + lane*16
    int srcoff[2], dstoff[2];
#pragma unroll
    for (int j = 0; j < 2; ++j) {
        int o = (w * 2 + j) * 1024 + lane * 16;
        int row = o >> 8, c = o & 255;
        srcoff[j] = row * 256 + (c ^ ((row & 7) << 4)); // pre-swizzled global source
        dstoff[j] = (w * 2 + j) * 1024;                 // wave-uniform LDS base
    }

    const char* Rb = (const char*)R;

    // swizzled read-offset components: lds_off(ct,kk) = ct*4096 + lbase + (kk*64 ^ m64)
    int m64 = (lr & 4) << 4;
    int lbase = lr * 256 + ((lk * 16) ^ ((lr & 3) << 4));

    float acc[4][4] = {};

#define STAGE(buf, jj)                                                            \
    do {                                                                          \
        const char* tb_ = Rb + (size_t)(jj) * TILE_BYTES;                         \
        _Pragma("unroll")                                                         \
        for (int j = 0; j < 2; ++j)                                               \
            __builtin_amdgcn_global_load_lds(                                     \
                (const __attribute__((address_space(1))) unsigned*)(tb_ + srcoff[j]), \
                (__attribute__((address_space(3))) unsigned*)(&smem[buf][dstoff[j]]), \
                16, 0, 0);                                                        \
    } while (0)

    // ct in {0,1}; DIAG => mask subtile where ct == r + ctd (ctd in {0,-2})
#define BATCH_BODY(DIAG)                                                          \
    do {                                                                          \
        _Pragma("unroll")                                                         \
        for (int ct = 0; ct < 2; ++ct) {                                          \
            const char* cb_ = sb + ct * 4096;                                     \
            bf16x8 b0 = *(const bf16x8*)(cb_ + (0 ^ m64));                        \
            bf16x8 b1 = *(const bf16x8*)(cb_ + (64 ^ m64));                       \
            bf16x8 b2 = *(const bf16x8*)(cb_ + (128 ^ m64));                      \
            bf16x8 b3 = *(const bf16x8*)(cb_ + (192 ^ m64));                      \
            _Pragma("unroll")                                                     \
            for (int r = 0; r < 4; ++r) {                                         \
                f32x4 c = {0.f, 0.f, 0.f, 0.f};                                   \
                c = __builtin_amdgcn_mfma_f32_16x16x32_bf16(afrag[r][0], b0, c, 0, 0, 0); \
                c = __builtin_amdgcn_mfma_f32_16x16x32_bf16(afrag[r][1], b1, c, 0, 0, 0); \
                c = __builtin_amdgcn_mfma_f32_16x16x32_bf16(afrag[r][2], b2, c, 0, 0, 0); \
                c = __builtin_amdgcn_mfma_f32_16x16x32_bf16(afrag[r][3], b3, c, 0, 0, 0); \
                if (DIAG && ct == r + ctd) {                                      \
                    _Pragma("unroll")                                             \
                    for (int q = 0; q < 4; ++q)                                   \
                        if (lk * 4 + q != lr) {                                   \
                            float e = fast_exp2(c[q]);                            \
                            acc[r][q] += e; csum[ct] += e;                        \
                        }                                                         \
                } else {                                                          \
                    _Pragma("unroll")                                             \
                    for (int q = 0; q < 4; ++q) {                                 \
                        float e = fast_exp2(c[q]);                                \
                        acc[r][q] += e; csum[ct] += e;                            \
                    }                                                             \
                }                                                                 \
            }                                                                     \
        }                                                                         \
    } while (0)

    if (nt > 0) STAGE(0, jstart);
    __syncthreads();                         // drains vmcnt(0) before first reads
    int cur = 0;
    for (int t = 0; t < nt; ++t) {
        int jt = jstart + (t << 4);
        int colBase = jt << 5;
        // flush PREVIOUS tile's column partials (one rotating wave, lanes<32;
        // parity (t-1)&1 != t&1, so no race with this tile's colacc writes)
        if (t > 0 && w == ((t + 3) & 3) && lane < 32) {
            int pcb = colBase - 512;         // (jt-16)<<5
            if (pcb >= rowBase + 256) {
                int par = (t - 1) & 1;
                float v = 0.f;
#pragma unroll
                for (int u = 0; u < 16; ++u) v += colacc[par][u][lane & 15][lane >> 4];
                colpart[colpart_off(I) + pcb + lane - ((I + 1) << 8)] = v;
            }
        }
        if (t + 1 < nt) STAGE(cur ^ 1, jt + 16);   // async prefetch, zero VGPR cost
        const char* sb = &smem[cur][0] + lbase;
        float csum[2] = {};
        int ctd = (waveRow - colBase) >> 4;  // wave-uniform, multiple of 2
        bool dg = (ctd == 0) || (ctd == -2); // tile intersects wave's diagonal
        if (dg) {
            BATCH_BODY(true);
        } else {
            BATCH_BODY(false);
        }
        bool offdiag = (colBase >= rowBase + 256);
        if (offdiag) {                       // one b64 per lane, conflict-free
            int par = t & 1;
            f32x2 cs = {csum[0], csum[1]};
            *(f32x2*)&colacc[par][(w << 2) | lk][lr][0] = cs;
        }
        __syncthreads();                     // orders smem dbuf + colacc publish
        cur ^= 1;
    }
    if (nt > 0 && w == ((nt + 3) & 3) && lane < 32) { // flush last tile
        int pcb = (jstart + ((nt - 1) << 4)) << 5;
        if (pcb >= rowBase + 256) {
            int par = (nt - 1) & 1;
            float v = 0.f;
#pragma unroll
            for (int u = 0; u < 16; ++u) v += colacc[par][u][lane & 15][lane >> 4];
            colpart[colpart_off(I) + pcb + lane - ((I + 1) << 8)] = v;
        }
    }
#undef STAGE
#undef BATCH_BODY

    // reduce the 16 col-lanes of each row group, write deterministic row partials
    // (empty lists still write zeros so k_negred can sum all 16 slabs)
#pragma unroll
    for (int r = 0; r < 4; ++r)
#pragma unroll
        for (int q = 0; q < 4; ++q) {
            float v = acc[r][q];
            v += __shfl_xor(v, 1);
            v += __shfl_xor(v, 2);
            v += __shfl_xor(v, 4);
            v += __shfl_xor(v, 8);
            if (lr == 0)
                rowpart[(size_t)s * NROWS + waveRow + r * 16 + lk * 4 + q] = v;
        }
}

// K2b: slice-parallel partial reduction of rowpart+colpart -> negp[8][N].
// 512 blocks; <=10 independent coalesced loads per thread.
__global__ __launch_bounds__(256) void k_negred(const float* __restrict__ rowpart,
                                                const float* __restrict__ colpart,
                                                float* __restrict__ negp) {
    int g = blockIdx.x >> 3;                // row group: rows [256g, 256g+256)
    int z = blockIdx.x & (NSLICE - 1);
    int i = g * 256 + threadIdx.x;
    float a = 0.f;
#pragma unroll
    for (int s = z; s < NSPLIT; s += NSLICE) // 2 iterations
        a += rowpart[(size_t)s * NROWS + i];
    for (int I = z; I < g; I += NSLICE)      // <=8 iterations
        a += colpart[colpart_off(I) + i - ((I + 1) << 8)];
    negp[(size_t)z * NROWS + i] = a;
}

// K3a: per-row loss terms + block partial sums. 64 blocks x 256 threads.
__global__ __launch_bounds__(256) void k_loss1(const float* __restrict__ pos,
                                               const float* __restrict__ negp,
                                               float* __restrict__ bsum) {
    int i = blockIdx.x * 256 + threadIdx.x;
    float neg = 0.f;
#pragma unroll
    for (int z = 0; z < NSLICE; ++z) neg += negp[(size_t)z * NROWS + i];
    neg *= E_M2; // folded (sim - 2.0) shift
    float p = pos[i & (B_ROWS - 1)];
    float Ng = fmaxf((neg - 819.2f * p) * (1.0f / 0.9f), 8192.0f * E_M2);
    float l = fast_log2((p + Ng + 1e-8f) / p) * 0.69314718056f; // = -log(p/(p+Ng+eps))
#pragma unroll
    for (int m = 32; m; m >>= 1) l += __shfl_xor(l, m);
    __shared__ float s4[4];
    int wv = threadIdx.x >> 6;
    if ((threadIdx.x & 63) == 0) s4[wv] = l;
    __syncthreads();
    if (threadIdx.x == 0) bsum[blockIdx.x] = s4[0] + s4[1] + s4[2] + s4[3];
}

// K3b: final reduce of 64 block sums. 1 block, 1 wave.
__global__ void k_loss2(const float* __restrict__ bsum, float* __restrict__ out) {
    float v = bsum[threadIdx.x];
#pragma unroll
    for (int m = 32; m; m >>= 1) v += __shfl_xor(v, m);
    if (threadIdx.x == 0) out[0] = v * (1.0f / (float)NROWS);
}

extern "C" void kernel_launch(void* const* d_in, const int* in_sizes, int n_in,
                              void* d_out, int out_size, void* d_ws, size_t ws_size,
                              hipStream_t stream) {
    const float* zi = (const float*)d_in[0];
    const float* zj = (const float*)d_in[1];
    char* ws = (char*)d_ws;
    unsigned short* reps = (unsigned short*)ws;            // 4 MB
    float* pos = (float*)(ws + 4194304);                   // 32 KB
    float* rowpart = pos + B_ROWS;                         // 16*16384*4 = 1 MB
    float* colpart = rowpart + (size_t)NSPLIT * NROWS;     // 516096*4 ~= 2 MB (triangular)
    float* negp = colpart + 516096;                        // 8*16384*4 = 512 KB
    float* bsum = negp + (size_t)NSLICE * NROWS;           // 256 B
    float* out = (float*)d_out;                            // total ~7.6 MB

    k_norm<<<B_ROWS / 4, 256, 0, stream>>>(zi, zj, (unsigned*)reps, pos);
    k_negsum<<<NBLK, 256, 0, stream>>>(reps, rowpart, colpart);
    k_negred<<<64 * NSLICE, 256, 0, stream>>>(rowpart, colpart, negp);
    k_loss1<<<NROWS / 256, 256, 0, stream>>>(pos, negp, bsum);
    k_loss2<<<1, 64, 0, stream>>>(bsum, out);
}